// Round 22
// baseline (102.009 us; speedup 1.0000x reference)
//
#include <hip/hip_runtime.h>

enum { B_ = 32, T_ = 1024, V_ = 512, S_ = 128 };

static constexpr float K2   = 1.4426950408889634f;  // 1/ln2
static constexpr float LN2F = 0.6931471805599453f;
#define BOOSTI 6

typedef float f32x4 __attribute__((ext_vector_type(4)));
#define AS1 __attribute__((address_space(1)))
#define AS3 __attribute__((address_space(3)))

#define DPPI(x, ctrl) __builtin_amdgcn_update_dpp(0, (x), (ctrl), 0xF, 0xF, true)
#define DPPF(x, ctrl) __int_as_float(DPPI(__float_as_int(x), (ctrl)))
#define DPP_WSR1(x) DPPF((x), 0x138)   // lane l <- lane l-1, lane 0 <- 0

__device__ __forceinline__ float dpp_wave_max_l63(float x) {
  x = fmaxf(x, DPPF(x, 0xB1));   x = fmaxf(x, DPPF(x, 0x4E));
  x = fmaxf(x, DPPF(x, 0x124));  x = fmaxf(x, DPPF(x, 0x128));
  x = fmaxf(x, DPPF(x, 0x142));  x = fmaxf(x, DPPF(x, 0x143));
  return x;
}

// Kernel A: per (b,t) fused logsumexp + masked linear-prob table.
// Q[b][t][lane] = (pe1*v1, pe3*v3, pb*v0, pb*v2); rows t >= len[b] skipped.
__global__ __launch_bounds__(256) void ctc_pre4(
    const float* __restrict__ logits, const int* __restrict__ targets,
    const int* __restrict__ loglen, const int* __restrict__ tgtlen,
    f32x4* __restrict__ Q) {
  const int w = threadIdx.x >> 6, l = threadIdx.x & 63;
  const int row = blockIdx.x * 4 + w;          // row = b*T + t
  const int b = row >> 10;
  const int t = row & (T_ - 1);
  if (t >= loglen[b]) return;                  // dead row: never consumed
  const float* lrow = logits + (size_t)row * V_;
  const float4* r4 = (const float4*)lrow;
  float4 a = r4[l], c = r4[l + 64];
  float s = __builtin_exp2f(a.x * K2) + __builtin_exp2f(a.y * K2) +
            __builtin_exp2f(a.z * K2) + __builtin_exp2f(a.w * K2) +
            __builtin_exp2f(c.x * K2) + __builtin_exp2f(c.y * K2) +
            __builtin_exp2f(c.z * K2) + __builtin_exp2f(c.w * K2);
  #pragma unroll
  for (int off = 32; off; off >>= 1) s += __shfl_xor(s, off, 64);
  const float sh = (float)BOOSTI - __builtin_log2f(s);

  const int2 ee = ((const int2*)(targets + b * S_))[l];
  const int tl = tgtlen[b];
  const float lgb = __shfl(a.x, 0, 64);        // blank logit (elem 0)
  const float lg1 = lrow[ee.x];
  const float lg3 = lrow[ee.y];
  const float pb  = __builtin_exp2f(fmaf(lgb, K2, sh));
  const float pe1 = __builtin_exp2f(fmaf(lg1, K2, sh));
  const float pe3 = __builtin_exp2f(fmaf(lg3, K2, sh));
  const int smax = 2 * tl;
  f32x4 q;
  q.x = (4 * l + 1 <= smax) ? pe1 : 0.0f;
  q.y = (4 * l + 3 <= smax) ? pe3 : 0.0f;
  q.z = (4 * l     <= smax) ? pb  : 0.0f;
  q.w = (4 * l + 2 <= smax) ? pb  : 0.0f;
  Q[(size_t)row * 64 + l] = q;
}

// Kernel B: dual-batch producer-consumer. 16 blocks x 3 waves:
// wave 0 consumes TWO batches (bA = blk, bB = blk+16) with interleaved
// independent COMPUTE chains (in-wave ILP hides dep stalls); waves 1,2 are
// per-batch R20-verbatim producers (global_load_lds chunks + flags).
__global__ __launch_bounds__(192, 1) void ctc_dp8(
    const f32x4* __restrict__ Q, const int* __restrict__ targets,
    const int* __restrict__ loglen, const int* __restrict__ tgtlen,
    float* __restrict__ out) {
  __shared__ f32x4 bufA[2][32 * 64];   // 2 x 32 KiB per batch
  __shared__ f32x4 bufB[2][32 * 64];
  __shared__ int flag_readyA[2], flag_readyB[2], flag_doneA[2], flag_doneB[2];
  __shared__ float Aa[257], Ab[257];
  const int wv = threadIdx.x >> 6, l = threadIdx.x & 63;
  const int bA = blockIdx.x, bB = blockIdx.x + 16;
  const int lenA = loglen[bA], lenB = loglen[bB];
  const int tlA = tgtlen[bA], tlB = tgtlen[bB];
  const int lenMax = lenA > lenB ? lenA : lenB;
  const int lenMin = lenA < lenB ? lenA : lenB;
  const int nch = (lenMax - 1 + 31) >> 5;
  const f32x4* QbA = Q + (size_t)bA * T_ * 64;
  const f32x4* QbB = Q + (size_t)bB * T_ * 64;

  if (threadIdx.x == 0) {
    flag_readyA[0] = flag_readyA[1] = 0; flag_readyB[0] = flag_readyB[1] = 0;
    flag_doneA[0] = flag_doneA[1] = 0;   flag_doneB[0] = flag_doneB[1] = 0;
  }
  __syncthreads();

  if (wv != 0) {
    // ---------------- producers (wave 1 -> A, wave 2 -> B) ----------------
    const f32x4* Qp = (wv == 1) ? QbA : QbB;
    f32x4* bufp = (wv == 1) ? &bufA[0][0] : &bufB[0][0];
    volatile int* fr = (wv == 1) ? (volatile int*)flag_readyA : (volatile int*)flag_readyB;
    volatile int* fd = (wv == 1) ? (volatile int*)flag_doneA : (volatile int*)flag_doneB;
    for (int c = 0; c < nch; ++c) {
      if (c >= 2) {
        while (fd[c & 1] < c - 1) __builtin_amdgcn_s_sleep(1);
      }
      const int r0 = 1 + 32 * c;
      #pragma unroll
      for (int i = 0; i < 32; ++i) {
        int row = r0 + i; if (row > T_ - 1) row = T_ - 1;
        __builtin_amdgcn_global_load_lds(
            (const AS1 void*)(const void*)(Qp + (size_t)row * 64 + l),
            (AS3 void*)(void*)(bufp + ((c & 1) * 2048 + i * 64)), 16, 0, 0);
      }
      asm volatile("s_waitcnt vmcnt(0)" ::: "memory");
      if (l == 0) fr[c & 1] = c + 1;
    }
    return;
  }

  // ---------------- consumer (wave 0, both batches) ----------------
  __builtin_amdgcn_s_setprio(1);

  const int2 eeA = ((const int2*)(targets + bA * S_))[l];
  const int2 eeB = ((const int2*)(targets + bB * S_))[l];
  const int e1A = eeA.x, e3A = eeA.y, e1B = eeB.x, e3B = eeB.y;
  const int em1A = __shfl_up(e3A, 1);
  const int em1B = __shfl_up(e3B, 1);
  const float m1A = ((l > 0) && (e1A != 0) && (e1A != em1A)) ? 1.0f : 0.0f;
  const float m3A = ((e3A != 0) && (e3A != e1A)) ? 1.0f : 0.0f;
  const float v4lA = ((l == 63) && (2 * tlA >= 256)) ? 1.0f : 0.0f;
  const float m1B = ((l > 0) && (e1B != 0) && (e1B != em1B)) ? 1.0f : 0.0f;
  const float m3B = ((e3B != 0) && (e3B != e1B)) ? 1.0f : 0.0f;
  const float v4lB = ((l == 63) && (2 * tlB >= 256)) ? 1.0f : 0.0f;

  f32x4 qiA = QbA[l];
  f32x4 qiB = QbB[l];
  float p0A = (l == 0) ? qiA.z : 0.0f, p1A = (l == 0) ? qiA.x : 0.0f;
  float p2A = 0.0f, p3A = 0.0f, p4A = 0.0f;
  float p0B = (l == 0) ? qiB.z : 0.0f, p1B = (l == 0) ? qiB.x : 0.0f;
  float p2B = 0.0f, p3B = 0.0f, p4B = 0.0f;

  const unsigned baseA = (unsigned)(uintptr_t)(AS3 char*)(void*)&bufA[0][0];
  const unsigned baseB = (unsigned)(uintptr_t)(AS3 char*)(void*)&bufB[0][0];

  asm volatile("s_waitcnt vmcnt(0) lgkmcnt(0)" ::: "memory");

  f32x4 qa0, qa1, qa2, qa3, qa4, qa5, qa6, qa7;
  f32x4 qb0, qb1, qb2, qb3, qb4, qb5, qb6, qb7;
#define DSRA(R, O) asm volatile("ds_read_b128 %0, %1 offset:" #O \
      : "=&v"(R) : "v"(vba))
#define DSRB(R, O) asm volatile("ds_read_b128 %0, %1 offset:" #O \
      : "=&v"(R) : "v"(vbb))
#define WT2(RA, RB, N) asm volatile("s_waitcnt lgkmcnt(" #N ")" \
      : "+v"(RA), "+v"(RB))

#define COMP(RX, S) { \
    const float n1_ = DPP_WSR1(p3##S); \
    const float w0_ = (p0##S + n1_) * RX.z; \
    const float w1_ = (p0##S + p1##S + n1_ * m1##S) * RX.x; \
    const float w2_ = (p1##S + p2##S) * RX.w; \
    const float w3_ = (p2##S + p3##S + p1##S * m3##S) * RX.y; \
    const float w4_ = (p4##S + p3##S) * RX.w * v4l##S; \
    p0##S = w0_; p1##S = w1_; p2##S = w2_; p3##S = w3_; p4##S = w4_; \
  }

#define REN(S) { \
    float m_ = fmaxf(fmaxf(fmaxf(p0##S, p1##S), fmaxf(p2##S, p3##S)), p4##S); \
    m_ = dpp_wave_max_l63(m_); \
    const int wm_ = __builtin_amdgcn_readlane(__float_as_int(m_), 63); \
    const int e_ = (wm_ >> 23) & 0xFF; \
    const float sc_ = __int_as_float((254 - e_) << 23); \
    p0##S *= sc_; p1##S *= sc_; p2##S *= sc_; p3##S *= sc_; p4##S *= sc_; \
    shift##S += e_ - 127; \
  }

  // fast: both batches active for the whole chunk
#define FS2(RA, RB, O) { WT2(RA, RB, 14); COMP(RA, A); COMP(RB, B); \
    DSRA(RA, O); DSRB(RB, O); }
#define FD2(RA, RB, N) { WT2(RA, RB, N); COMP(RA, A); COMP(RB, B); }
  // guarded: per-step, per-batch length guards
#define GS2(RA, RB, O, i) { WT2(RA, RB, 14); \
    if (t0 + (i) < lenA) COMP(RA, A); \
    if (t0 + (i) < lenB) COMP(RB, B); \
    DSRA(RA, O); DSRB(RB, O); }
#define GD2(RA, RB, N, i) { WT2(RA, RB, N); \
    if (t0 + (i) < lenA) COMP(RA, A); \
    if (t0 + (i) < lenB) COMP(RB, B); }

  int shiftA = 0, shiftB = 0;
  for (int c = 0; c < nch; ++c) {
    const int t0 = 1 + 32 * c;
    while (((volatile int*)flag_readyA)[c & 1] < c + 1) __builtin_amdgcn_s_sleep(1);
    while (((volatile int*)flag_readyB)[c & 1] < c + 1) __builtin_amdgcn_s_sleep(1);
    const unsigned vba = baseA + (unsigned)(c & 1) * 32768u + (unsigned)l * 16u;
    const unsigned vbb = baseB + (unsigned)(c & 1) * 32768u + (unsigned)l * 16u;

    // prologue: rows 0..7 of the chunk, strictly A,B-alternating issue
    DSRA(qa0, 0);    DSRB(qb0, 0);
    DSRA(qa1, 1024); DSRB(qb1, 1024);
    DSRA(qa2, 2048); DSRB(qb2, 2048);
    DSRA(qa3, 3072); DSRB(qb3, 3072);
    DSRA(qa4, 4096); DSRB(qb4, 4096);
    DSRA(qa5, 5120); DSRB(qb5, 5120);
    DSRA(qa6, 6144); DSRB(qb6, 6144);
    DSRA(qa7, 7168); DSRB(qb7, 7168);

    if (t0 + 31 < lenMin) {
      FS2(qa0, qb0, 8192)  FS2(qa1, qb1, 9216)  FS2(qa2, qb2, 10240) FS2(qa3, qb3, 11264)
      FS2(qa4, qb4, 12288) FS2(qa5, qb5, 13312) FS2(qa6, qb6, 14336) FS2(qa7, qb7, 15360)
      FS2(qa0, qb0, 16384) FS2(qa1, qb1, 17408) FS2(qa2, qb2, 18432) FS2(qa3, qb3, 19456)
      FS2(qa4, qb4, 20480) FS2(qa5, qb5, 21504) FS2(qa6, qb6, 22528) FS2(qa7, qb7, 23552)
      REN(A) REN(B)
      FS2(qa0, qb0, 24576) FS2(qa1, qb1, 25600) FS2(qa2, qb2, 26624) FS2(qa3, qb3, 27648)
      FS2(qa4, qb4, 28672) FS2(qa5, qb5, 29696) FS2(qa6, qb6, 30720) FS2(qa7, qb7, 31744)
      FD2(qa0, qb0, 14) FD2(qa1, qb1, 12) FD2(qa2, qb2, 10) FD2(qa3, qb3, 8)
      FD2(qa4, qb4, 6)  FD2(qa5, qb5, 4)  FD2(qa6, qb6, 2)  FD2(qa7, qb7, 0)
      REN(A) REN(B)
    } else {
      GS2(qa0, qb0, 8192, 0)   GS2(qa1, qb1, 9216, 1)   GS2(qa2, qb2, 10240, 2)  GS2(qa3, qb3, 11264, 3)
      GS2(qa4, qb4, 12288, 4)  GS2(qa5, qb5, 13312, 5)  GS2(qa6, qb6, 14336, 6)  GS2(qa7, qb7, 15360, 7)
      GS2(qa0, qb0, 16384, 8)  GS2(qa1, qb1, 17408, 9)  GS2(qa2, qb2, 18432, 10) GS2(qa3, qb3, 19456, 11)
      GS2(qa4, qb4, 20480, 12) GS2(qa5, qb5, 21504, 13) GS2(qa6, qb6, 22528, 14) GS2(qa7, qb7, 23552, 15)
      REN(A) REN(B)
      GS2(qa0, qb0, 24576, 16) GS2(qa1, qb1, 25600, 17) GS2(qa2, qb2, 26624, 18) GS2(qa3, qb3, 27648, 19)
      GS2(qa4, qb4, 28672, 20) GS2(qa5, qb5, 29696, 21) GS2(qa6, qb6, 30720, 22) GS2(qa7, qb7, 31744, 23)
      GD2(qa0, qb0, 14, 24) GD2(qa1, qb1, 12, 25) GD2(qa2, qb2, 10, 26) GD2(qa3, qb3, 8, 27)
      GD2(qa4, qb4, 6, 28)  GD2(qa5, qb5, 4, 29)  GD2(qa6, qb6, 2, 30)  GD2(qa7, qb7, 0, 31)
      REN(A) REN(B)
    }

    asm volatile("s_waitcnt lgkmcnt(0)" ::: "memory");
    if (l == 0) {
      ((volatile int*)flag_doneA)[c & 1] = c + 1;
      ((volatile int*)flag_doneB)[c & 1] = c + 1;
    }
  }

  // readout both batches
  Aa[4 * l + 0] = p0A; Aa[4 * l + 1] = p1A;
  Aa[4 * l + 2] = p2A; Aa[4 * l + 3] = p3A;
  Ab[4 * l + 0] = p0B; Ab[4 * l + 1] = p1B;
  Ab[4 * l + 2] = p2B; Ab[4 * l + 3] = p3B;
  if (l == 63) { Aa[256] = p4A; Ab[256] = p4B; }
  asm volatile("s_waitcnt lgkmcnt(0)" ::: "memory");
  if (l == 0) {
    {
      const int ib = 2 * tlA;
      const int il = (ib - 1) > 0 ? ib - 1 : 0;
      const float ab = Aa[ib];
      const float al = (tlA > 0) ? Aa[il] : 0.0f;
      out[bA] = -(__builtin_log2f(ab + al) + (float)(shiftA - BOOSTI * lenA)) * LN2F;
    }
    {
      const int ib = 2 * tlB;
      const int il = (ib - 1) > 0 ? ib - 1 : 0;
      const float ab = Ab[ib];
      const float al = (tlB > 0) ? Ab[il] : 0.0f;
      out[bB] = -(__builtin_log2f(ab + al) + (float)(shiftB - BOOSTI * lenB)) * LN2F;
    }
  }
}

extern "C" void kernel_launch(void* const* d_in, const int* in_sizes, int n_in,
                              void* d_out, int out_size, void* d_ws, size_t ws_size,
                              hipStream_t stream) {
  const float* logits  = (const float*)d_in[0];
  const int*   targets = (const int*)d_in[1];
  const int*   loglen  = (const int*)d_in[2];
  const int*   tgtlen  = (const int*)d_in[3];
  float* out = (float*)d_out;
  f32x4* Q = (f32x4*)d_ws;   // 32 MiB (proven sufficient R8-R21)

  ctc_pre4<<<(B_ * T_) / 4, 256, 0, stream>>>(logits, targets, loglen, tgtlen, Q);
  ctc_dp8<<<B_ / 2, 192, 0, stream>>>(Q, targets, loglen, tgtlen, out);
}

// Round 23
// 59.269 us; speedup vs baseline: 1.7211x; 1.7211x over previous
//
#include <hip/hip_runtime.h>

enum { B_ = 32, T_ = 1024, V_ = 512, S_ = 128 };

static constexpr float K2   = 1.4426950408889634f;  // 1/ln2
static constexpr float LN2F = 0.6931471805599453f;
#define BOOSTI 6

typedef float f32x4 __attribute__((ext_vector_type(4)));
#define AS1 __attribute__((address_space(1)))
#define AS3 __attribute__((address_space(3)))

#define DPPI(x, ctrl) __builtin_amdgcn_update_dpp(0, (x), (ctrl), 0xF, 0xF, true)
#define DPPF(x, ctrl) __int_as_float(DPPI(__float_as_int(x), (ctrl)))
#define DPP_WSR1(x) DPPF((x), 0x138)   // lane l <- lane l-1, lane 0 <- 0

__device__ __forceinline__ float dpp_wave_max_l63(float x) {
  x = fmaxf(x, DPPF(x, 0xB1));   x = fmaxf(x, DPPF(x, 0x4E));
  x = fmaxf(x, DPPF(x, 0x124));  x = fmaxf(x, DPPF(x, 0x128));
  x = fmaxf(x, DPPF(x, 0x142));  x = fmaxf(x, DPPF(x, 0x143));
  return x;
}

// Kernel A: per (b,t) fused logsumexp + masked linear-prob table.
// Q[b][t][lane] = (pe1*v1, pe3*v3, pb*v0, pb*v2); rows t >= len[b] skipped.
__global__ __launch_bounds__(256) void ctc_pre4(
    const float* __restrict__ logits, const int* __restrict__ targets,
    const int* __restrict__ loglen, const int* __restrict__ tgtlen,
    f32x4* __restrict__ Q) {
  const int w = threadIdx.x >> 6, l = threadIdx.x & 63;
  const int row = blockIdx.x * 4 + w;          // row = b*T + t
  const int b = row >> 10;
  const int t = row & (T_ - 1);
  if (t >= loglen[b]) return;                  // dead row: never consumed
  const float* lrow = logits + (size_t)row * V_;
  const float4* r4 = (const float4*)lrow;
  float4 a = r4[l], c = r4[l + 64];
  float s = __builtin_exp2f(a.x * K2) + __builtin_exp2f(a.y * K2) +
            __builtin_exp2f(a.z * K2) + __builtin_exp2f(a.w * K2) +
            __builtin_exp2f(c.x * K2) + __builtin_exp2f(c.y * K2) +
            __builtin_exp2f(c.z * K2) + __builtin_exp2f(c.w * K2);
  #pragma unroll
  for (int off = 32; off; off >>= 1) s += __shfl_xor(s, off, 64);
  const float sh = (float)BOOSTI - __builtin_log2f(s);

  const int2 ee = ((const int2*)(targets + b * S_))[l];
  const int tl = tgtlen[b];
  const float lgb = __shfl(a.x, 0, 64);        // blank logit (elem 0)
  const float lg1 = lrow[ee.x];
  const float lg3 = lrow[ee.y];
  const float pb  = __builtin_exp2f(fmaf(lgb, K2, sh));
  const float pe1 = __builtin_exp2f(fmaf(lg1, K2, sh));
  const float pe3 = __builtin_exp2f(fmaf(lg3, K2, sh));
  const int smax = 2 * tl;
  f32x4 q;
  q.x = (4 * l + 1 <= smax) ? pe1 : 0.0f;
  q.y = (4 * l + 3 <= smax) ? pe3 : 0.0f;
  q.z = (4 * l     <= smax) ? pb  : 0.0f;
  q.w = (4 * l + 2 <= smax) ? pb  : 0.0f;
  Q[(size_t)row * 64 + l] = q;
}

// Kernel B: producer-consumer (R21-proven) with a 13-VALU COMPUTE:
//  - fmaf(n1,m1,..)/fmaf(p1,m3,..): m∈{0,1} so the product is exact and the
//    fma rounds identically to the old mul+add chain (bit-identical).
//  - v4l multiply dropped: lanes!=63 accumulate garbage p4, but A[256] is
//    only read from lane 63 (where RX.w == pb when tl==128), and renorm's
//    scale choice is power-of-2 exactly-compensated -> output bit-identical.
__global__ __launch_bounds__(128, 1) void ctc_dp7(
    const f32x4* __restrict__ Q, const int* __restrict__ targets,
    const int* __restrict__ loglen, const int* __restrict__ tgtlen,
    float* __restrict__ out) {
  __shared__ f32x4 buf[2][32 * 64];   // 2 x 32 KiB chunks
  __shared__ int flag_ready[2];
  __shared__ int flag_done[2];
  __shared__ float A[257];
  const int wv = threadIdx.x >> 6, l = threadIdx.x & 63;
  const int b = blockIdx.x;
  const int len = loglen[b], tl = tgtlen[b];
  const int nch = (len - 1 + 31) >> 5;
  const f32x4* Qb = Q + (size_t)b * T_ * 64;

  if (threadIdx.x == 0) {
    flag_ready[0] = 0; flag_ready[1] = 0;
    flag_done[0] = 0;  flag_done[1] = 0;
  }
  __syncthreads();

  if (wv == 1) {
    // ---------------- producer ----------------
    for (int c = 0; c < nch; ++c) {
      if (c >= 2) {
        while (((volatile int*)flag_done)[c & 1] < c - 1)
          __builtin_amdgcn_s_sleep(1);
      }
      const int r0 = 1 + 32 * c;
      #pragma unroll
      for (int i = 0; i < 32; ++i) {
        int row = r0 + i; if (row > T_ - 1) row = T_ - 1;
        __builtin_amdgcn_global_load_lds(
            (const AS1 void*)(const void*)(Qb + (size_t)row * 64 + l),
            (AS3 void*)(void*)(&buf[c & 1][i * 64]), 16, 0, 0);
      }
      asm volatile("s_waitcnt vmcnt(0)" ::: "memory");
      if (l == 0) ((volatile int*)flag_ready)[c & 1] = c + 1;
    }
    return;
  }

  // ---------------- consumer ----------------
  __builtin_amdgcn_s_setprio(1);

  const int2 ee = ((const int2*)(targets + b * S_))[l];
  const int e1 = ee.x, e3 = ee.y;
  const int em1 = __shfl_up(e3, 1);
  const float m1 = ((l > 0) && (e1 != 0) && (e1 != em1)) ? 1.0f : 0.0f;
  const float m3 = ((e3 != 0) && (e3 != e1)) ? 1.0f : 0.0f;

  f32x4 qi = Qb[l];                    // t = 0 init
  float p0 = (l == 0) ? qi.z : 0.0f;
  float p1 = (l == 0) ? qi.x : 0.0f;
  float p2 = 0.0f, p3 = 0.0f, p4 = 0.0f;

  const unsigned bufbase = (unsigned)(uintptr_t)(AS3 char*)(void*)&buf[0][0];

  f32x4 q0, q1, q2, q3, q4, q5, q6, q7;
#define DSRO(R, O) asm volatile("ds_read_b128 %0, %1 offset:" #O \
      : "=&v"(R) : "v"(vb))
#define WTL(R, N) asm volatile("s_waitcnt lgkmcnt(" #N ")" : "+v"(R))
#define WAIT8 asm volatile("s_waitcnt lgkmcnt(0)" \
      : "+v"(q0), "+v"(q1), "+v"(q2), "+v"(q3), \
        "+v"(q4), "+v"(q5), "+v"(q6), "+v"(q7))

#define COMPUTE(RX) { \
    const float n1_  = DPP_WSR1(p3); \
    const float w0_ = (p0 + n1_) * RX.z; \
    const float w1_ = fmaf(n1_, m1, p0 + p1) * RX.x; \
    const float w2_ = (p1 + p2) * RX.w; \
    const float w3_ = fmaf(p1, m3, p2 + p3) * RX.y; \
    const float w4_ = (p4 + p3) * RX.w; \
    p0 = w0_; p1 = w1_; p2 = w2_; p3 = w3_; p4 = w4_; \
  }

#define RENORM { \
    float m_ = fmaxf(fmaxf(fmaxf(p0, p1), fmaxf(p2, p3)), p4); \
    m_ = dpp_wave_max_l63(m_); \
    const int wm_ = __builtin_amdgcn_readlane(__float_as_int(m_), 63); \
    const int e_ = (wm_ >> 23) & 0xFF; \
    const float sc_ = __int_as_float((254 - e_) << 23); \
    p0 *= sc_; p1 *= sc_; p2 *= sc_; p3 *= sc_; p4 *= sc_; \
    shift += e_ - 127; \
  }

#define CR(R, O)  { COMPUTE(R); DSRO(R, O); }
#define TS(R, O, i)  { WTL(R, 7); if (t0 + (i) < len) COMPUTE(R); DSRO(R, O); }
#define TD(R, N, i)  { WTL(R, N); if (t0 + (i) < len) COMPUTE(R); }

  int shift = 0;
  for (int c = 0; c < nch; ++c) {
    const int t0 = 1 + 32 * c;
    while (((volatile int*)flag_ready)[c & 1] < c + 1)
      __builtin_amdgcn_s_sleep(1);
    const unsigned vb = bufbase + (unsigned)(c & 1) * 32768u + (unsigned)l * 16u;

    DSRO(q0, 0);    DSRO(q1, 1024); DSRO(q2, 2048); DSRO(q3, 3072);
    DSRO(q4, 4096); DSRO(q5, 5120); DSRO(q6, 6144); DSRO(q7, 7168);

    if (t0 + 31 < len) {
      WAIT8;   // rows 0-7 ready
      CR(q0, 8192)  CR(q1, 9216)  CR(q2, 10240) CR(q3, 11264)
      CR(q4, 12288) CR(q5, 13312) CR(q6, 14336) CR(q7, 15360)
      WAIT8;   // rows 8-15 ready
      CR(q0, 16384) CR(q1, 17408) CR(q2, 18432) CR(q3, 19456)
      CR(q4, 20480) CR(q5, 21504) CR(q6, 22528) CR(q7, 23552)
      RENORM
      WAIT8;   // rows 16-23 ready
      CR(q0, 24576) CR(q1, 25600) CR(q2, 26624) CR(q3, 27648)
      CR(q4, 28672) CR(q5, 29696) CR(q6, 30720) CR(q7, 31744)
      WAIT8;   // rows 24-31 ready
      COMPUTE(q0) COMPUTE(q1) COMPUTE(q2) COMPUTE(q3)
      COMPUTE(q4) COMPUTE(q5) COMPUTE(q6) COMPUTE(q7)
      RENORM
    } else {
      TS(q0, 8192, 0)   TS(q1, 9216, 1)   TS(q2, 10240, 2)  TS(q3, 11264, 3)
      TS(q4, 12288, 4)  TS(q5, 13312, 5)  TS(q6, 14336, 6)  TS(q7, 15360, 7)
      TS(q0, 16384, 8)  TS(q1, 17408, 9)  TS(q2, 18432, 10) TS(q3, 19456, 11)
      TS(q4, 20480, 12) TS(q5, 21504, 13) TS(q6, 22528, 14) TS(q7, 23552, 15)
      TS(q0, 24576, 16) TS(q1, 25600, 17) TS(q2, 26624, 18) TS(q3, 27648, 19)
      TS(q4, 28672, 20) TS(q5, 29696, 21) TS(q6, 30720, 22) TS(q7, 31744, 23)
      TD(q0, 7, 24) TD(q1, 6, 25) TD(q2, 5, 26) TD(q3, 4, 27)
      TD(q4, 3, 28) TD(q5, 2, 29) TD(q6, 1, 30) TD(q7, 0, 31)
    }

    asm volatile("s_waitcnt lgkmcnt(0)" ::: "memory");
    if (l == 0) ((volatile int*)flag_done)[c & 1] = c + 1;
  }

  A[4 * l + 0] = p0; A[4 * l + 1] = p1;
  A[4 * l + 2] = p2; A[4 * l + 3] = p3;
  if (l == 63) A[256] = p4;
  asm volatile("s_waitcnt lgkmcnt(0)" ::: "memory");
  if (l == 0) {
    const int ib = 2 * tl;
    const int il = (ib - 1) > 0 ? ib - 1 : 0;
    const float ab = A[ib];
    const float al = (tl > 0) ? A[il] : 0.0f;
    out[b] = -(__builtin_log2f(ab + al) + (float)(shift - BOOSTI * len)) * LN2F;
  }
}

extern "C" void kernel_launch(void* const* d_in, const int* in_sizes, int n_in,
                              void* d_out, int out_size, void* d_ws, size_t ws_size,
                              hipStream_t stream) {
  const float* logits  = (const float*)d_in[0];
  const int*   targets = (const int*)d_in[1];
  const int*   loglen  = (const int*)d_in[2];
  const int*   tgtlen  = (const int*)d_in[3];
  float* out = (float*)d_out;
  f32x4* Q = (f32x4*)d_ws;   // 32 MiB (proven sufficient R8-R22)

  ctc_pre4<<<(B_ * T_) / 4, 256, 0, stream>>>(logits, targets, loglen, tgtlen, Q);
  ctc_dp7<<<B_, 128, 0, stream>>>(Q, targets, loglen, tgtlen, out);
}